// Round 7
// baseline (159.162 us; speedup 1.0000x reference)
//
#include <hip/hip_runtime.h>
#include <math.h>

#define NPTS 200
#define NCH  13
#define BLK  256
#define FPB  (NPTS * NCH)          // 2600 floats per batch
#define STG  2560                  // floats staged in LDS: covers points 0..191 fully

// 4-byte-aligned float4 for dword-aligned (not 16B-aligned) vector loads
typedef float f4u __attribute__((ext_vector_type(4), aligned(4)));

// 12-byte packed store (align 4) for coalesced per-point output
typedef struct { float x, y, z; } f3s;

#define ACCUMULATE(Q0,Q1,Q2,Q3,Q4,Q5,Q6,Q7,Q8,Q9,Q10,Q11,Q12)               \
    {                                                                        \
        float wt = aa * (Q0) + bb;                                           \
        wt = fmaxf(wt, 0.f) + 1e-8f;                                         \
        const float v1x = fmaf(shift, (Q7),  (Q1));                          \
        const float v1y = fmaf(shift, (Q8),  (Q2));                          \
        const float v1z = fmaf(shift, (Q9),  (Q3));                          \
        const float v2x = fmaf(shift, (Q10), (Q4));                          \
        const float v2y = fmaf(shift, (Q11), (Q5));                          \
        const float v2z = fmaf(shift, (Q12), (Q6));                          \
        const float wv2x = wt * v2x, wv2y = wt * v2y, wv2z = wt * v2z;       \
        acc[0] += wt;                                                        \
        acc[1] += wt * v1x; acc[2] += wt * v1y; acc[3] += wt * v1z;          \
        acc[4] += wv2x;     acc[5] += wv2y;     acc[6] += wv2z;              \
        acc[7]  += wv2x * v1x; acc[8]  += wv2x * v1y; acc[9]  += wv2x * v1z; \
        acc[10] += wv2y * v1x; acc[11] += wv2y * v1y; acc[12] += wv2y * v1z; \
        acc[13] += wv2z * v1x; acc[14] += wv2z * v1y; acc[15] += wv2z * v1z; \
    }

// Symmetric 4x4 Jacobi rotation on pair (P,Q). Exact same math as the
// proven full-update version (app' = app - t*apq, a'kp = c*akp - s*akq),
// but exploiting symmetry: 2 diag FMAs + 8 off-diag FMAs instead of two
// full 4-wide row/col loops (32 FMAs). e1p/e1q, e2p/e2q are the symmetric
// storage names of elements (k,P),(k,Q) for the two k not in {P,Q}.
#define ROT(dp, dq, opq, e1p, e1q, e2p, e2q, P, Q)                           \
    {                                                                        \
        const float apq = opq;                                               \
        if (apq != 0.0f) {               /* wave-uniform branch */           \
            const float tau = (dq - dp) * 0.5f * __builtin_amdgcn_rcpf(apq); \
            const float tt  = copysignf(1.0f, tau) * __builtin_amdgcn_rcpf(  \
                                fabsf(tau) +                                 \
                                __builtin_amdgcn_sqrtf(fmaf(tau, tau, 1.0f)));\
            const float c = __builtin_amdgcn_rsqf(fmaf(tt, tt, 1.0f));       \
            const float s = tt * c;                                          \
            dp -= tt * apq;                                                  \
            dq += tt * apq;                                                  \
            opq = 0.0f;                                                      \
            { const float t1 = e1p; e1p = c * t1 - s * e1q;                  \
              e1q = s * t1 + c * e1q; }                                      \
            { const float t2 = e2p; e2p = c * t2 - s * e2q;                  \
              e2q = s * t2 + c * e2q; }                                      \
            _Pragma("unroll")                                                \
            for (int k = 0; k < 4; ++k) {                                    \
                const float a1 = Vm[k][P], a2 = Vm[k][Q];                    \
                Vm[k][P] = c * a1 - s * a2;                                  \
                Vm[k][Q] = s * a1 + c * a2;                                  \
            }                                                                \
        }                                                                    \
    }

// ---------------------------------------------------------------------------
// Fused v6: zero barriers. QCP (v5) failed on near-degenerate eigen-gaps;
// reverted to the PROVEN iterative Jacobi (absmax 0.015625 in v2/v4) with
// two issue-cost reductions:
//   (a) symmetric-update rotations (~40 VALU/rot vs 62)
//   (b) 4 sweeps instead of 5 (quadratic convergence; 7x absmax headroom)
// plus v5's global_load_lds staging (round-1 byte-exact, proven) which
// removes the stride-52 TA divergence v4 paid ~11us for.
// Structure: stage -> accumulate (xyz2 in regs) -> 6-level shfl_xor
// butterfly -> all-lane redundant Jacobi (wave-uniform) -> apply from regs.
// ---------------------------------------------------------------------------
__global__ __launch_bounds__(BLK, 4) void fused_kernel(
    const float* __restrict__ net_in,   // (B, 200, 13)
    const float* __restrict__ shift_p,
    const float* __restrict__ a_p,
    const float* __restrict__ b_p,
    float* __restrict__ out)            // (B, 200, 3)
{
    __shared__ float s_in[4 * STG];       // 40,960 B exactly -> 4 blocks/CU

    const int tid = threadIdx.x;
    const int w   = tid >> 6;             // wave id = local batch
    const int l   = tid & 63;
    const int b   = blockIdx.x * 4 + w;   // global batch

    const float shift = shift_p[0];
    const float aa    = a_p[0];
    const float bb    = b_p[0];

    const float* src = net_in + (size_t)b * FPB;
    float*       dst = s_in + w * STG;    // wave-private LDS region

    // ---- async stage: 640 float4 -> LDS (points 0..191 fully covered) ----
    #pragma unroll
    for (int jj = 0; jj < 10; ++jj) {
        __builtin_amdgcn_global_load_lds(
            (const __attribute__((address_space(1))) void*)(src + jj * 256 + l * 4),
            (__attribute__((address_space(3))) void*)(dst + jj * 256),
            16, 0, 0);
    }

    // ---- tail points 192..199 direct to registers (same vmcnt drain) ----
    f4u t0v = {0.f, 0.f, 0.f, 0.f};
    f4u t1v = {0.f, 0.f, 0.f, 0.f};
    f4u t2v = {0.f, 0.f, 0.f, 0.f};
    float t12 = 0.f;
    if (l < 8) {
        const float* tp = src + (192 + l) * NCH;
        t0v = *(const f4u*)(tp);        // q0..q3
        t1v = *(const f4u*)(tp + 4);    // q4..q7
        t2v = *(const f4u*)(tp + 8);    // q8..q11
        t12 = tp[12];                   // q12
    }

    __builtin_amdgcn_s_waitcnt(0);          // drain staging + tail
    __asm__ __volatile__("" ::: "memory");  // keep LDS reads below the wait

    // ---- per-lane accumulation; save xyz2 in regs for the apply step ----
    float acc[16];
    #pragma unroll
    for (int k = 0; k < 16; ++k) acc[k] = 0.f;

    float sx2[4], sy2[4], sz2[4];

    #pragma unroll
    for (int jj = 0; jj < 3; ++jj) {
        const int p = l + 64 * jj;        // stride 13 dwords: 2-way LDS = free
        const float* q = dst + p * NCH;
        const float q0 = q[0],  q1 = q[1],  q2  = q[2],  q3  = q[3];
        const float q4 = q[4],  q5 = q[5],  q6  = q[6],  q7  = q[7];
        const float q8 = q[8],  q9 = q[9],  q10 = q[10], q11 = q[11], q12 = q[12];
        ACCUMULATE(q0, q1, q2, q3, q4, q5, q6, q7, q8, q9, q10, q11, q12)
        sx2[jj] = q4; sy2[jj] = q5; sz2[jj] = q6;
    }
    sx2[3] = t1v.x; sy2[3] = t1v.y; sz2[3] = t1v.z;   // zeros for l>=8
    if (l < 8) {
        ACCUMULATE(t0v.x, t0v.y, t0v.z, t0v.w,
                   t1v.x, t1v.y, t1v.z, t1v.w,
                   t2v.x, t2v.y, t2v.z, t2v.w, t12)
    }

    // ---- full 64-lane xor-butterfly: every lane ends with all 16 totals ----
    #pragma unroll
    for (int k = 0; k < 16; ++k) {
        acc[k] += __shfl_xor(acc[k], 32, 64);
        acc[k] += __shfl_xor(acc[k], 16, 64);
        acc[k] += __shfl_xor(acc[k],  8, 64);
        acc[k] += __shfl_xor(acc[k],  4, 64);
        acc[k] += __shfl_xor(acc[k],  2, 64);
        acc[k] += __shfl_xor(acc[k],  1, 64);
    }

    // ---- centroids and centered covariance S ----
    const float W = acc[0];
    const float invW = __builtin_amdgcn_rcpf(W);
    const float v1cx = acc[1] * invW, v1cy = acc[2] * invW, v1cz = acc[3] * invW;
    const float v2cx = acc[4] * invW, v2cy = acc[5] * invW, v2cz = acc[6] * invW;

    const float Sxx = acc[7]  - W * v2cx * v1cx;
    const float Sxy = acc[8]  - W * v2cx * v1cy;
    const float Sxz = acc[9]  - W * v2cx * v1cz;
    const float Syx = acc[10] - W * v2cy * v1cx;
    const float Syy = acc[11] - W * v2cy * v1cy;
    const float Syz = acc[12] - W * v2cy * v1cz;
    const float Szx = acc[13] - W * v2cz * v1cx;
    const float Szy = acc[14] - W * v2cz * v1cy;
    const float Szz = acc[15] - W * v2cz * v1cz;

    // ---- Horn K matrix in symmetric storage (diag d0..d3, off oPQ) ----
    float d0  = Sxx + Syy + Szz;
    float o01 = Syz - Szy;
    float o02 = Szx - Sxz;
    float o03 = Sxy - Syx;
    float d1  = Sxx - Syy - Szz;
    float o12 = Sxy + Syx;
    float o13 = Szx + Sxz;
    float d2  = -Sxx + Syy - Szz;
    float o23 = Syz + Szy;
    float d3  = -Sxx - Syy + Szz;

    float Vm[4][4] = {{1,0,0,0},{0,1,0,0},{0,0,1,0},{0,0,0,1}};

    // 4 sweeps x 6 symmetric rotations, redundant on all 64 lanes
    for (int sweep = 0; sweep < 4; ++sweep) {
        ROT(d0, d1, o01,  o02, o12,  o03, o13,  0, 1)
        ROT(d0, d2, o02,  o01, o12,  o03, o23,  0, 2)
        ROT(d0, d3, o03,  o01, o13,  o02, o23,  0, 3)
        ROT(d1, d2, o12,  o01, o02,  o13, o23,  1, 2)
        ROT(d1, d3, o13,  o01, o03,  o12, o23,  1, 3)
        ROT(d2, d3, o23,  o02, o03,  o12, o13,  2, 3)
    }

    // ---- best eigenvector: constant-indexed compare chain ----
    float bd = d0;
    float q0 = Vm[0][0], qx = Vm[1][0], qy = Vm[2][0], qz = Vm[3][0];
    if (d1 > bd) { bd = d1; q0 = Vm[0][1]; qx = Vm[1][1]; qy = Vm[2][1]; qz = Vm[3][1]; }
    if (d2 > bd) { bd = d2; q0 = Vm[0][2]; qx = Vm[1][2]; qy = Vm[2][2]; qz = Vm[3][2]; }
    if (d3 > bd) { bd = d3; q0 = Vm[0][3]; qx = Vm[1][3]; qy = Vm[2][3]; qz = Vm[3][3]; }

    // renormalize (approx rotations leave ~1e-5 norm drift)
    const float qn = __builtin_amdgcn_rsqf(q0*q0 + qx*qx + qy*qy + qz*qz);
    q0 *= qn; qx *= qn; qy *= qn; qz *= qn;

    const float R00 = q0*q0 + qx*qx - qy*qy - qz*qz;
    const float R01 = 2.0f * (qx*qy - q0*qz);
    const float R02 = 2.0f * (qx*qz + q0*qy);
    const float R10 = 2.0f * (qx*qy + q0*qz);
    const float R11 = q0*q0 - qx*qx + qy*qy - qz*qz;
    const float R12 = 2.0f * (qy*qz - q0*qx);
    const float R20 = 2.0f * (qx*qz - q0*qy);
    const float R21 = 2.0f * (qy*qz + q0*qx);
    const float R22 = q0*q0 - qx*qx - qy*qy + qz*qz;

    const float tx = v1cx - (R00 * v2cx + R01 * v2cy + R02 * v2cz);
    const float ty = v1cy - (R10 * v2cx + R11 * v2cy + R12 * v2cz);
    const float tz = v1cz - (R20 * v2cx + R21 * v2cy + R22 * v2cz);

    // ---- apply from registers; coalesced 12B/lane stores ----
    float* ob = out + (size_t)b * (NPTS * 3);
    #pragma unroll
    for (int jj = 0; jj < 4; ++jj) {
        if (jj < 3 || l < 8) {
            const int p = l + 64 * jj;
            const float X = sx2[jj], Y = sy2[jj], Z = sz2[jj];
            f3s o3;
            o3.x = R00 * X + R01 * Y + R02 * Z + tx;
            o3.y = R10 * X + R11 * Y + R12 * Z + ty;
            o3.z = R20 * X + R21 * Y + R22 * Z + tz;
            *(f3s*)(ob + p * 3) = o3;
        }
    }
}

extern "C" void kernel_launch(void* const* d_in, const int* in_sizes, int n_in,
                              void* d_out, int out_size, void* d_ws, size_t ws_size,
                              hipStream_t stream) {
    const float* net_in  = (const float*)d_in[0];
    const float* shift_p = (const float*)d_in[1];
    const float* a_p     = (const float*)d_in[2];
    const float* b_p     = (const float*)d_in[3];
    float* out = (float*)d_out;

    const int B = in_sizes[0] / FPB;             // 8192
    (void)d_ws; (void)ws_size; (void)n_in; (void)out_size;

    fused_kernel<<<B / 4, BLK, 0, stream>>>(net_in, shift_p, a_p, b_p, out);
}

// Round 9
// 137.124 us; speedup vs baseline: 1.1607x; 1.1607x over previous
//
#include <hip/hip_runtime.h>
#include <math.h>

#define NPTS 200
#define NCH  13
#define BLK  256
#define FPB  (NPTS * NCH)          // 2600 floats per batch

// 4-byte-aligned float4 for dword-aligned (not 16B-aligned) vector loads
typedef float f4u __attribute__((ext_vector_type(4), aligned(4)));

// 12-byte packed store (align 4) for coalesced per-point output
typedef struct { float x, y, z; } f3s;

#define ACCUMULATE(Q0,Q1,Q2,Q3,Q4,Q5,Q6,Q7,Q8,Q9,Q10,Q11,Q12)               \
    {                                                                        \
        float wt = aa * (Q0) + bb;                                           \
        wt = fmaxf(wt, 0.f) + 1e-8f;                                         \
        const float v1x = fmaf(shift, (Q7),  (Q1));                          \
        const float v1y = fmaf(shift, (Q8),  (Q2));                          \
        const float v1z = fmaf(shift, (Q9),  (Q3));                          \
        const float v2x = fmaf(shift, (Q10), (Q4));                          \
        const float v2y = fmaf(shift, (Q11), (Q5));                          \
        const float v2z = fmaf(shift, (Q12), (Q6));                          \
        const float wv2x = wt * v2x, wv2y = wt * v2y, wv2z = wt * v2z;       \
        acc[0] += wt;                                                        \
        acc[1] += wt * v1x; acc[2] += wt * v1y; acc[3] += wt * v1z;          \
        acc[4] += wv2x;     acc[5] += wv2y;     acc[6] += wv2z;              \
        acc[7]  += wv2x * v1x; acc[8]  += wv2x * v1y; acc[9]  += wv2x * v1z; \
        acc[10] += wv2y * v1x; acc[11] += wv2y * v1y; acc[12] += wv2y * v1z; \
        acc[13] += wv2z * v1x; acc[14] += wv2z * v1y; acc[15] += wv2z * v1z; \
    }

// Branchless symmetric 4x4 Jacobi rotation on pair (P,Q). Same math as the
// HW-verified v6 ROT (absmax 0.015625), but with the apq==0 skip converted
// to an identity rotation via cndmask (data now differs per half-wave, so
// the branch is no longer wave-uniform). apq==0 => tt=0 => c=1,s=0 =>
// identity (dp/dq unchanged, updates no-op) — identical to the old skip.
// NaN guard: apq==0 && dq==dp makes tau=0*inf=NaN; the select kills it.
#define ROTB(dp, dq, opq, e1p, e1q, e2p, e2q, P, Q)                          \
    {                                                                        \
        const float apq = opq;                                               \
        const float tau = (dq - dp) * 0.5f * __builtin_amdgcn_rcpf(apq);     \
        float tt = copysignf(1.0f, tau) * __builtin_amdgcn_rcpf(             \
                     fabsf(tau) +                                            \
                     __builtin_amdgcn_sqrtf(fmaf(tau, tau, 1.0f)));          \
        tt = (apq != 0.0f) ? tt : 0.0f;                                      \
        const float c = __builtin_amdgcn_rsqf(fmaf(tt, tt, 1.0f));           \
        const float s = tt * c;                                              \
        dp -= tt * apq;                                                      \
        dq += tt * apq;                                                      \
        opq = 0.0f;                                                          \
        { const float t1 = e1p; e1p = c * t1 - s * e1q;                      \
          e1q = s * t1 + c * e1q; }                                          \
        { const float t2 = e2p; e2p = c * t2 - s * e2q;                      \
          e2q = s * t2 + c * e2q; }                                          \
        _Pragma("unroll")                                                    \
        for (int k = 0; k < 4; ++k) {                                        \
            const float a1 = Vm[k][P], a2 = Vm[k][Q];                        \
            Vm[k][P] = c * a1 - s * a2;                                      \
            Vm[k][Q] = s * a1 + c * a2;                                      \
        }                                                                    \
    }

// ---------------------------------------------------------------------------
// Fused v7 (resubmit — round 8 was an infra failure; round 4->5 proved the
// same error recurs and clears with an identical source):
// HALF-WAVE BATCH PAIRING. Lanes 0-31 own batch 2i, lanes 32-63 own batch
// 2i+1 — one instruction stream serves TWO batches:
//   - redundant solve + butterfly + R-build issued once per 2 batches
//     (the dominant per-wave serial tail is halved per batch)
//   - 4096 waves total, grid = 1024 blocks -> ENTIRE grid co-resident
//     (4 blocks/CU, no LDS, VGPR<=128), zero dispatch churn
//   - direct f4u loads (v4-proven; v6 showed staging+full-drain = net -5us)
//   - 5-level shfl_xor butterfly within 32-lane halves
//   - branchless per-lane Jacobi (4 sweeps, symmetric updates, HW-approx —
//     all HW-verified at absmax 0.015625 in v6)
// Zero LDS, zero barriers, zero cross-wave communication.
// ---------------------------------------------------------------------------
__global__ __launch_bounds__(BLK, 4) void fused_kernel(
    const float* __restrict__ net_in,   // (B, 200, 13)
    const float* __restrict__ shift_p,
    const float* __restrict__ a_p,
    const float* __restrict__ b_p,
    float* __restrict__ out)            // (B, 200, 3)
{
    const int tid = threadIdx.x;
    const int w   = tid >> 6;             // wave id in block
    const int l   = tid & 63;
    const int t   = l & 31;               // lane within half
    const int b   = (blockIdx.x * 4 + w) * 2 + (l >> 5);  // per-half batch

    const float shift = shift_p[0];
    const float aa    = a_p[0];
    const float bb    = b_p[0];

    const float* src = net_in + (size_t)b * FPB;

    // ---- per-lane accumulation: 32 lanes per batch, 200 = 6*32 + 8 ----
    float acc[16];
    #pragma unroll
    for (int k = 0; k < 16; ++k) acc[k] = 0.f;

    float sx2[7], sy2[7], sz2[7];

    #pragma unroll
    for (int i = 0; i < 7; ++i) {
        if (i < 6 || t < 8) {             // i<6 always valid; i==6 only t<8
            const float* q = src + (t + 32 * i) * NCH;
            const f4u v0 = *(const f4u*)(q);      // w, x1,y1,z1
            const f4u v1 = *(const f4u*)(q + 4);  // x2,y2,z2, n1x
            const f4u v2 = *(const f4u*)(q + 8);  // n1y,n1z, n2x,n2y
            const float q12 = q[12];              // n2z
            ACCUMULATE(v0.x, v0.y, v0.z, v0.w,
                       v1.x, v1.y, v1.z, v1.w,
                       v2.x, v2.y, v2.z, v2.w, q12)
            sx2[i] = v1.x; sy2[i] = v1.y; sz2[i] = v1.z;
        } else {
            sx2[i] = 0.f; sy2[i] = 0.f; sz2[i] = 0.f;
        }
    }

    // ---- 5-level xor-butterfly within each 32-lane half ----
    #pragma unroll
    for (int k = 0; k < 16; ++k) {
        acc[k] += __shfl_xor(acc[k], 16, 64);
        acc[k] += __shfl_xor(acc[k],  8, 64);
        acc[k] += __shfl_xor(acc[k],  4, 64);
        acc[k] += __shfl_xor(acc[k],  2, 64);
        acc[k] += __shfl_xor(acc[k],  1, 64);
    }

    // ---- centroids and centered covariance S (per half) ----
    const float W = acc[0];
    const float invW = __builtin_amdgcn_rcpf(W);
    const float v1cx = acc[1] * invW, v1cy = acc[2] * invW, v1cz = acc[3] * invW;
    const float v2cx = acc[4] * invW, v2cy = acc[5] * invW, v2cz = acc[6] * invW;

    const float Sxx = acc[7]  - W * v2cx * v1cx;
    const float Sxy = acc[8]  - W * v2cx * v1cy;
    const float Sxz = acc[9]  - W * v2cx * v1cz;
    const float Syx = acc[10] - W * v2cy * v1cx;
    const float Syy = acc[11] - W * v2cy * v1cy;
    const float Syz = acc[12] - W * v2cy * v1cz;
    const float Szx = acc[13] - W * v2cz * v1cx;
    const float Szy = acc[14] - W * v2cz * v1cy;
    const float Szz = acc[15] - W * v2cz * v1cz;

    // ---- Horn K matrix in symmetric storage (diag d0..d3, off oPQ) ----
    float d0  = Sxx + Syy + Szz;
    float o01 = Syz - Szy;
    float o02 = Szx - Sxz;
    float o03 = Sxy - Syx;
    float d1  = Sxx - Syy - Szz;
    float o12 = Sxy + Syx;
    float o13 = Szx + Sxz;
    float d2  = -Sxx + Syy - Szz;
    float o23 = Syz + Szy;
    float d3  = -Sxx - Syy + Szz;

    float Vm[4][4] = {{1,0,0,0},{0,1,0,0},{0,0,1,0},{0,0,0,1}};

    // 4 sweeps x 6 branchless symmetric rotations (issued once per 2 batches)
    for (int sweep = 0; sweep < 4; ++sweep) {
        ROTB(d0, d1, o01,  o02, o12,  o03, o13,  0, 1)
        ROTB(d0, d2, o02,  o01, o12,  o03, o23,  0, 2)
        ROTB(d0, d3, o03,  o01, o13,  o02, o23,  0, 3)
        ROTB(d1, d2, o12,  o01, o02,  o13, o23,  1, 2)
        ROTB(d1, d3, o13,  o01, o03,  o12, o23,  1, 3)
        ROTB(d2, d3, o23,  o02, o03,  o12, o13,  2, 3)
    }

    // ---- best eigenvector: branchless compare chain (per-lane data) ----
    float bd = d0;
    float q0 = Vm[0][0], qx = Vm[1][0], qy = Vm[2][0], qz = Vm[3][0];
    { const bool c1 = d1 > bd;
      bd = c1 ? d1 : bd;
      q0 = c1 ? Vm[0][1] : q0; qx = c1 ? Vm[1][1] : qx;
      qy = c1 ? Vm[2][1] : qy; qz = c1 ? Vm[3][1] : qz; }
    { const bool c2 = d2 > bd;
      bd = c2 ? d2 : bd;
      q0 = c2 ? Vm[0][2] : q0; qx = c2 ? Vm[1][2] : qx;
      qy = c2 ? Vm[2][2] : qy; qz = c2 ? Vm[3][2] : qz; }
    { const bool c3 = d3 > bd;
      q0 = c3 ? Vm[0][3] : q0; qx = c3 ? Vm[1][3] : qx;
      qy = c3 ? Vm[2][3] : qy; qz = c3 ? Vm[3][3] : qz; }

    // renormalize (approx rotations leave ~1e-5 norm drift)
    const float qn = __builtin_amdgcn_rsqf(q0*q0 + qx*qx + qy*qy + qz*qz);
    q0 *= qn; qx *= qn; qy *= qn; qz *= qn;

    const float R00 = q0*q0 + qx*qx - qy*qy - qz*qz;
    const float R01 = 2.0f * (qx*qy - q0*qz);
    const float R02 = 2.0f * (qx*qz + q0*qy);
    const float R10 = 2.0f * (qx*qy + q0*qz);
    const float R11 = q0*q0 - qx*qx + qy*qy - qz*qz;
    const float R12 = 2.0f * (qy*qz - q0*qx);
    const float R20 = 2.0f * (qx*qz - q0*qy);
    const float R21 = 2.0f * (qy*qz + q0*qx);
    const float R22 = q0*q0 - qx*qx - qy*qy + qz*qz;

    const float tx = v1cx - (R00 * v2cx + R01 * v2cy + R02 * v2cz);
    const float ty = v1cy - (R10 * v2cx + R11 * v2cy + R12 * v2cz);
    const float tz = v1cz - (R20 * v2cx + R21 * v2cy + R22 * v2cz);

    // ---- apply from registers; 12B/lane stores, 2 contiguous 384B runs ----
    float* ob = out + (size_t)b * (NPTS * 3);
    #pragma unroll
    for (int i = 0; i < 7; ++i) {
        if (i < 6 || t < 8) {
            const int p = t + 32 * i;
            const float X = sx2[i], Y = sy2[i], Z = sz2[i];
            f3s o3;
            o3.x = R00 * X + R01 * Y + R02 * Z + tx;
            o3.y = R10 * X + R11 * Y + R12 * Z + ty;
            o3.z = R20 * X + R21 * Y + R22 * Z + tz;
            *(f3s*)(ob + p * 3) = o3;
        }
    }
}

extern "C" void kernel_launch(void* const* d_in, const int* in_sizes, int n_in,
                              void* d_out, int out_size, void* d_ws, size_t ws_size,
                              hipStream_t stream) {
    const float* net_in  = (const float*)d_in[0];
    const float* shift_p = (const float*)d_in[1];
    const float* a_p     = (const float*)d_in[2];
    const float* b_p     = (const float*)d_in[3];
    float* out = (float*)d_out;

    const int B = in_sizes[0] / FPB;             // 8192
    (void)d_ws; (void)ws_size; (void)n_in; (void)out_size;

    // 8 batches per block (4 waves x 2 half-wave batches) -> 1024 blocks
    fused_kernel<<<B / 8, BLK, 0, stream>>>(net_in, shift_p, a_p, b_p, out);
}

// Round 10
// 136.287 us; speedup vs baseline: 1.1678x; 1.0061x over previous
//
#include <hip/hip_runtime.h>
#include <math.h>

#define NPTS 200
#define NCH  13
#define BLK  256
#define FPB  (NPTS * NCH)          // 2600 floats per batch

// 4-byte-aligned float4 for dword-aligned (not 16B-aligned) vector loads
typedef float f4u __attribute__((ext_vector_type(4), aligned(4)));

// 12-byte packed store (align 4) for coalesced per-point output
typedef struct { float x, y, z; } f3s;

#define ACCUMULATE(Q0,Q1,Q2,Q3,Q4,Q5,Q6,Q7,Q8,Q9,Q10,Q11,Q12)               \
    {                                                                        \
        float wt = aa * (Q0) + bb;                                           \
        wt = fmaxf(wt, 0.f) + 1e-8f;                                         \
        const float v1x = fmaf(shift, (Q7),  (Q1));                          \
        const float v1y = fmaf(shift, (Q8),  (Q2));                          \
        const float v1z = fmaf(shift, (Q9),  (Q3));                          \
        const float v2x = fmaf(shift, (Q10), (Q4));                          \
        const float v2y = fmaf(shift, (Q11), (Q5));                          \
        const float v2z = fmaf(shift, (Q12), (Q6));                          \
        const float wv2x = wt * v2x, wv2y = wt * v2y, wv2z = wt * v2z;       \
        acc[0] += wt;                                                        \
        acc[1] += wt * v1x; acc[2] += wt * v1y; acc[3] += wt * v1z;          \
        acc[4] += wv2x;     acc[5] += wv2y;     acc[6] += wv2z;              \
        acc[7]  += wv2x * v1x; acc[8]  += wv2x * v1y; acc[9]  += wv2x * v1z; \
        acc[10] += wv2y * v1x; acc[11] += wv2y * v1y; acc[12] += wv2y * v1z; \
        acc[13] += wv2z * v1x; acc[14] += wv2z * v1y; acc[15] += wv2z * v1z; \
    }

// Branchless symmetric 4x4 Jacobi rotation on pair (P,Q). Same math as the
// HW-verified v6/v7 ROTB (absmax 0.015625). apq==0 => tt=0 => c=1,s=0 =>
// identity rotation; NaN from tau=0*inf is killed by the select.
#define ROTB(dp, dq, opq, e1p, e1q, e2p, e2q, P, Q)                          \
    {                                                                        \
        const float apq = opq;                                               \
        const float tau = (dq - dp) * 0.5f * __builtin_amdgcn_rcpf(apq);     \
        float tt = copysignf(1.0f, tau) * __builtin_amdgcn_rcpf(             \
                     fabsf(tau) +                                            \
                     __builtin_amdgcn_sqrtf(fmaf(tau, tau, 1.0f)));          \
        tt = (apq != 0.0f) ? tt : 0.0f;                                      \
        const float c = __builtin_amdgcn_rsqf(fmaf(tt, tt, 1.0f));           \
        const float s = tt * c;                                              \
        dp -= tt * apq;                                                      \
        dq += tt * apq;                                                      \
        opq = 0.0f;                                                          \
        { const float t1 = e1p; e1p = c * t1 - s * e1q;                      \
          e1q = s * t1 + c * e1q; }                                          \
        { const float t2 = e2p; e2p = c * t2 - s * e2q;                      \
          e2q = s * t2 + c * e2q; }                                          \
        _Pragma("unroll")                                                    \
        for (int k = 0; k < 4; ++k) {                                        \
            const float a1 = Vm[k][P], a2 = Vm[k][Q];                        \
            Vm[k][P] = c * a1 - s * a2;                                      \
            Vm[k][Q] = s * a1 + c * a2;                                      \
        }                                                                    \
    }

// ---------------------------------------------------------------------------
// Fused v8: QUARTER-WAVE BATCH PACKING. Lanes [16g,16g+15] own batch 4i+g —
// one instruction stream serves FOUR batches:
//   - redundant solve + butterfly tail issued once per 4 batches; the
//     system-wide count of serial solve chains (the lever that paid in
//     v6->v7: 8192->4096 chains = -20us) halves again: 4096->2048
//   - 2048 waves, grid = 512 blocks -> fully co-resident (2 blocks/CU)
//   - __launch_bounds__(256,2): at 8 waves/CU the grid is the occupancy
//     limiter anyway, so the 256-VGPR cap is free and lets the compiler
//     hoist more of the 52 loads/wave (less latency exposure at 2 w/SIMD)
//   - direct f4u loads (TA line-span per instruction unchanged: 4x13=52)
//   - 4-level shfl_xor butterfly within 16-lane groups
//   - branchless 4-sweep symmetric Jacobi (HW-verified absmax 0.015625)
// Zero LDS, zero barriers, zero cross-wave communication.
// ---------------------------------------------------------------------------
__global__ __launch_bounds__(BLK, 2) void fused_kernel(
    const float* __restrict__ net_in,   // (B, 200, 13)
    const float* __restrict__ shift_p,
    const float* __restrict__ a_p,
    const float* __restrict__ b_p,
    float* __restrict__ out)            // (B, 200, 3)
{
    const int tid = threadIdx.x;
    const int w   = tid >> 6;             // wave id in block
    const int l   = tid & 63;
    const int t   = l & 15;               // lane within quarter
    const int b   = (blockIdx.x * 4 + w) * 4 + (l >> 4);  // per-quarter batch

    const float shift = shift_p[0];
    const float aa    = a_p[0];
    const float bb    = b_p[0];

    const float* src = net_in + (size_t)b * FPB;

    // ---- per-lane accumulation: 16 lanes per batch, 200 = 12*16 + 8 ----
    float acc[16];
    #pragma unroll
    for (int k = 0; k < 16; ++k) acc[k] = 0.f;

    float sx2[13], sy2[13], sz2[13];

    #pragma unroll
    for (int i = 0; i < 13; ++i) {
        if (i < 12 || t < 8) {            // i<12 always valid; i==12 only t<8
            const float* q = src + (t + 16 * i) * NCH;
            const f4u v0 = *(const f4u*)(q);      // w, x1,y1,z1
            const f4u v1 = *(const f4u*)(q + 4);  // x2,y2,z2, n1x
            const f4u v2 = *(const f4u*)(q + 8);  // n1y,n1z, n2x,n2y
            const float q12 = q[12];              // n2z
            ACCUMULATE(v0.x, v0.y, v0.z, v0.w,
                       v1.x, v1.y, v1.z, v1.w,
                       v2.x, v2.y, v2.z, v2.w, q12)
            sx2[i] = v1.x; sy2[i] = v1.y; sz2[i] = v1.z;
        } else {
            sx2[i] = 0.f; sy2[i] = 0.f; sz2[i] = 0.f;
        }
    }

    // ---- 4-level xor-butterfly within each 16-lane quarter ----
    #pragma unroll
    for (int k = 0; k < 16; ++k) {
        acc[k] += __shfl_xor(acc[k],  8, 64);
        acc[k] += __shfl_xor(acc[k],  4, 64);
        acc[k] += __shfl_xor(acc[k],  2, 64);
        acc[k] += __shfl_xor(acc[k],  1, 64);
    }

    // ---- centroids and centered covariance S (per quarter) ----
    const float W = acc[0];
    const float invW = __builtin_amdgcn_rcpf(W);
    const float v1cx = acc[1] * invW, v1cy = acc[2] * invW, v1cz = acc[3] * invW;
    const float v2cx = acc[4] * invW, v2cy = acc[5] * invW, v2cz = acc[6] * invW;

    const float Sxx = acc[7]  - W * v2cx * v1cx;
    const float Sxy = acc[8]  - W * v2cx * v1cy;
    const float Sxz = acc[9]  - W * v2cx * v1cz;
    const float Syx = acc[10] - W * v2cy * v1cx;
    const float Syy = acc[11] - W * v2cy * v1cy;
    const float Syz = acc[12] - W * v2cy * v1cz;
    const float Szx = acc[13] - W * v2cz * v1cx;
    const float Szy = acc[14] - W * v2cz * v1cy;
    const float Szz = acc[15] - W * v2cz * v1cz;

    // ---- Horn K matrix in symmetric storage (diag d0..d3, off oPQ) ----
    float d0  = Sxx + Syy + Szz;
    float o01 = Syz - Szy;
    float o02 = Szx - Sxz;
    float o03 = Sxy - Syx;
    float d1  = Sxx - Syy - Szz;
    float o12 = Sxy + Syx;
    float o13 = Szx + Sxz;
    float d2  = -Sxx + Syy - Szz;
    float o23 = Syz + Szy;
    float d3  = -Sxx - Syy + Szz;

    float Vm[4][4] = {{1,0,0,0},{0,1,0,0},{0,0,1,0},{0,0,0,1}};

    // 4 sweeps x 6 branchless symmetric rotations (issued once per 4 batches)
    for (int sweep = 0; sweep < 4; ++sweep) {
        ROTB(d0, d1, o01,  o02, o12,  o03, o13,  0, 1)
        ROTB(d0, d2, o02,  o01, o12,  o03, o23,  0, 2)
        ROTB(d0, d3, o03,  o01, o13,  o02, o23,  0, 3)
        ROTB(d1, d2, o12,  o01, o02,  o13, o23,  1, 2)
        ROTB(d1, d3, o13,  o01, o03,  o12, o23,  1, 3)
        ROTB(d2, d3, o23,  o02, o03,  o12, o13,  2, 3)
    }

    // ---- best eigenvector: branchless compare chain (per-lane data) ----
    float bd = d0;
    float q0 = Vm[0][0], qx = Vm[1][0], qy = Vm[2][0], qz = Vm[3][0];
    { const bool c1 = d1 > bd;
      bd = c1 ? d1 : bd;
      q0 = c1 ? Vm[0][1] : q0; qx = c1 ? Vm[1][1] : qx;
      qy = c1 ? Vm[2][1] : qy; qz = c1 ? Vm[3][1] : qz; }
    { const bool c2 = d2 > bd;
      bd = c2 ? d2 : bd;
      q0 = c2 ? Vm[0][2] : q0; qx = c2 ? Vm[1][2] : qx;
      qy = c2 ? Vm[2][2] : qy; qz = c2 ? Vm[3][2] : qz; }
    { const bool c3 = d3 > bd;
      q0 = c3 ? Vm[0][3] : q0; qx = c3 ? Vm[1][3] : qx;
      qy = c3 ? Vm[2][3] : qy; qz = c3 ? Vm[3][3] : qz; }

    // renormalize (approx rotations leave ~1e-5 norm drift)
    const float qn = __builtin_amdgcn_rsqf(q0*q0 + qx*qx + qy*qy + qz*qz);
    q0 *= qn; qx *= qn; qy *= qn; qz *= qn;

    const float R00 = q0*q0 + qx*qx - qy*qy - qz*qz;
    const float R01 = 2.0f * (qx*qy - q0*qz);
    const float R02 = 2.0f * (qx*qz + q0*qy);
    const float R10 = 2.0f * (qx*qy + q0*qz);
    const float R11 = q0*q0 - qx*qx + qy*qy - qz*qz;
    const float R12 = 2.0f * (qy*qz - q0*qx);
    const float R20 = 2.0f * (qx*qz - q0*qy);
    const float R21 = 2.0f * (qy*qz + q0*qx);
    const float R22 = q0*q0 - qx*qx - qy*qy + qz*qz;

    const float tx = v1cx - (R00 * v2cx + R01 * v2cy + R02 * v2cz);
    const float ty = v1cy - (R10 * v2cx + R11 * v2cy + R12 * v2cz);
    const float tz = v1cz - (R20 * v2cx + R21 * v2cy + R22 * v2cz);

    // ---- apply from registers; 12B/lane stores, 4 contiguous 192B runs ----
    float* ob = out + (size_t)b * (NPTS * 3);
    #pragma unroll
    for (int i = 0; i < 13; ++i) {
        if (i < 12 || t < 8) {
            const int p = t + 16 * i;
            const float X = sx2[i], Y = sy2[i], Z = sz2[i];
            f3s o3;
            o3.x = R00 * X + R01 * Y + R02 * Z + tx;
            o3.y = R10 * X + R11 * Y + R12 * Z + ty;
            o3.z = R20 * X + R21 * Y + R22 * Z + tz;
            *(f3s*)(ob + p * 3) = o3;
        }
    }
}

extern "C" void kernel_launch(void* const* d_in, const int* in_sizes, int n_in,
                              void* d_out, int out_size, void* d_ws, size_t ws_size,
                              hipStream_t stream) {
    const float* net_in  = (const float*)d_in[0];
    const float* shift_p = (const float*)d_in[1];
    const float* a_p     = (const float*)d_in[2];
    const float* b_p     = (const float*)d_in[3];
    float* out = (float*)d_out;

    const int B = in_sizes[0] / FPB;             // 8192
    (void)d_ws; (void)ws_size; (void)n_in; (void)out_size;

    // 16 batches per block (4 waves x 4 quarter-wave batches) -> 512 blocks
    fused_kernel<<<B / 16, BLK, 0, stream>>>(net_in, shift_p, a_p, b_p, out);
}